// Round 8
// baseline (500.032 us; speedup 1.0000x reference)
//
#include <hip/hip_runtime.h>
#include <hip/hip_bf16.h>
#include <stdint.h>

#define BB 16
#define NN 2048
#define DD 64
#define BM 64
#define BN 64
#define KSTR 72   // K/Vt LDS row stride in bf16 elems (144 B: 16B-aligned)
#define PSTR 72   // P LDS row stride

typedef __attribute__((ext_vector_type(8))) short short8;
typedef __attribute__((ext_vector_type(4))) float f32x4;

__device__ __forceinline__ unsigned short f2bf(float f) {   // RNE
  union { float f; uint32_t u; } c; c.f = f;
  uint32_t u = c.u + 0x7fffu + ((c.u >> 16) & 1u);
  return (unsigned short)(u >> 16);
}
__device__ __forceinline__ uint32_t pkrn(float a, float b) { // packed f32x2 -> bf16x2
  union { __hip_bfloat162 h; uint32_t u; } c;
  c.h = __float22bfloat162_rn(make_float2(a, b));
  return c.u;
}

// ---- pre-pass ----
// blocks [0,512):   V fp32 -> bf16 transposed vt[b][d][key]
// blocks [512,528): per-batch counting sort of queries by valid + zero split counters
// blocks [528,592): V fp32 tile-suffix sums suf[b][t][d], t=0..32
__global__ __launch_bounds__(256) void prep_kernel(const float* __restrict__ v,
                                                   const int* __restrict__ valid,
                                                   unsigned short* __restrict__ vt,
                                                   int* __restrict__ perm,
                                                   int* __restrict__ sval,
                                                   float* __restrict__ suf,
                                                   int* __restrict__ cnt) {
  __shared__ float t[64][65];
  __shared__ int hist[2048];
  __shared__ int part[256];
  __shared__ float ts[32][16];
  int id = blockIdx.x, tid = threadIdx.x;
  if (id < 512) {
    int b = id >> 5;
    int k0 = (id & 31) * 64;
    const float4* src = (const float4*)(v + ((size_t)b * NN + k0) * DD);
#pragma unroll
    for (int i = 0; i < 4; i++) {
      int f4 = tid + i * 256;
      int row = f4 >> 4, c4 = f4 & 15;
      float4 f = src[f4];
      t[row][c4*4+0] = f.x; t[row][c4*4+1] = f.y; t[row][c4*4+2] = f.z; t[row][c4*4+3] = f.w;
    }
    __syncthreads();
    int d = tid >> 2, kg = tid & 3;
    unsigned short* dst = vt + ((size_t)b * DD + d) * NN + k0 + kg * 16;
#pragma unroll
    for (int u = 0; u < 4; u++) {
      ushort4 o;
      o.x = f2bf(t[kg*16+u*4+0][d]);
      o.y = f2bf(t[kg*16+u*4+1][d]);
      o.z = f2bf(t[kg*16+u*4+2][d]);
      o.w = f2bf(t[kg*16+u*4+3][d]);
      ((ushort4*)dst)[u] = o;
    }
  } else if (id < 528) {
    // counting sort of queries by valid, ascending; also zero split counters
    int b = id - 512;
    if (tid < 32) cnt[b * 32 + tid] = 0;    // ws is 0xAA-poisoned: must zero
    for (int i = tid; i < 2048; i += 256) hist[i] = 0;
    __syncthreads();
    for (int i = tid; i < NN; i += 256) atomicAdd(&hist[valid[b * NN + i]], 1);
    __syncthreads();
    int base = tid * 8, loc[8], s = 0;
#pragma unroll
    for (int j = 0; j < 8; j++) { loc[j] = s; s += hist[base + j]; }
    part[tid] = s;
    __syncthreads();
    if (tid == 0) {
      int run = 0;
      for (int t2 = 0; t2 < 256; t2++) { int tmp = part[t2]; part[t2] = run; run += tmp; }
    }
    __syncthreads();
#pragma unroll
    for (int j = 0; j < 8; j++) hist[base + j] = part[tid] + loc[j];
    __syncthreads();
    for (int i = tid; i < NN; i += 256) {
      int vv = valid[b * NN + i];
      int pos = atomicAdd(&hist[vv], 1);
      perm[b * NN + pos] = i;
      sval[b * NN + pos] = vv;
    }
  } else {
    // fp32 V suffix sums at 64-key tile granularity: suf[b][t][d] = sum_{j>=t*64} V[b][j][d]
    int sb = id - 528;               // 64 blocks: b = sb>>2, d-group = sb&3
    int b = sb >> 2, dg = sb & 3;
    for (int p = tid; p < 512; p += 256) {
      int tt = p >> 4, d0 = p & 15;
      const float* vp = v + ((size_t)b * NN + tt * 64) * DD + dg * 16 + d0;
      float s = 0.0f;
#pragma unroll 8
      for (int r = 0; r < 64; r++) s += vp[(size_t)r * DD];
      ts[tt][d0] = s;
    }
    __syncthreads();
    if (tid < 16) {
      int d = dg * 16 + tid;
      float acc = 0.0f;
      suf[((size_t)b * 33 + 32) * 64 + d] = 0.0f;
      for (int tt = 31; tt >= 0; tt--) {
        acc += ts[tt][tid];
        suf[((size_t)b * 33 + tt) * 64 + d] = acc;
      }
    }
  }
}

// ---- main flash-attention: sorted ranks + suffix shortcut + split-K with
// ---- last-block fixup (no separate combine kernel). K converted fp32->bf16
// ---- inline, OFF the staging critical path (convert after compute phase).
template <int NS>
__global__ __launch_bounds__(256, 4) void attn_kernel(
    const float* __restrict__ q, const float* __restrict__ kin,
    const unsigned short* __restrict__ vtbf, const int* __restrict__ perm,
    const int* __restrict__ sval, const float* __restrict__ suf,
    float* __restrict__ out, unsigned short* __restrict__ po,
    float* __restrict__ pz, int* __restrict__ cnt)
{
  constexpr int JLEN = NN / NS;

  __shared__ __align__(16) unsigned short Klds[BN * KSTR];
  __shared__ __align__(16) unsigned short Vlds[DD * KSTR];
  __shared__ __align__(16) unsigned short Plds[4 * 16 * PSTR];
  __shared__ int vld[BM];
  __shared__ int pidx[BM];
  __shared__ int lastFlag;

  // decode: id&7 = XCD; heavy rank-tiles (large valid) dispatch first
  int id = blockIdx.x;
  int b = (id & 7) + 8 * ((id >> 3) & 1);
  int rest = id >> 4;                 // [0, 32*NS)
  int sp = rest % NS;
  int qt = 31 - (rest / NS);          // reversed: heavy blocks first
  int i0 = qt * BM;                   // RANK base (sorted by valid)
  int jbase = sp * JLEN;
  int rangeEnd = jbase + JLEN;

  int tid = threadIdx.x;
  int w = tid >> 6, lane = tid & 63;
  int m = lane & 15, quad = lane >> 4;

  if (tid < BM) {
    vld[tid]  = sval[b * NN + i0 + tid];
    pidx[tid] = perm[b * NN + i0 + tid];
  }
  int maxv = sval[b * NN + i0 + 63];  // sorted ascending -> block max (uniform)
  int jcov = ((maxv + 63) >> 6) << 6; // keys needing per-key scores
  int niter = (min(rangeEnd, jcov) - jbase) >> 6;
  if (niter < 0) niter = 0;
  int Tp = (jbase >> 6) + niter;      // first closed-form tile in this range

  __syncthreads();

  f32x4 o[4] = {{0,0,0,0},{0,0,0,0},{0,0,0,0},{0,0,0,0}};
  float z = 0.0f;
  const float CM = 1.0000010f;        // exp(1e-6): masked-key weight (NOT zero)

  if (niter > 0) {
    int vq = vld[w * 16 + m];
    int qrow = pidx[w * 16 + m];

    // Q fragment (B-operand layout), scale 0.125 folded, fp32->bf16
    short8 qf[2];
    {
      const float* qp = q + ((size_t)b * NN + qrow) * DD;
#pragma unroll
      for (int s = 0; s < 2; s++) {
        float4 f0 = *(const float4*)(qp + s * 32 + quad * 8);
        float4 f1 = *(const float4*)(qp + s * 32 + quad * 8 + 4);
        union { short8 v; uint32_t x[4]; } tmp;
        tmp.x[0] = pkrn(f0.x * 0.125f, f0.y * 0.125f);
        tmp.x[1] = pkrn(f0.z * 0.125f, f0.w * 0.125f);
        tmp.x[2] = pkrn(f1.x * 0.125f, f1.y * 0.125f);
        tmp.x[3] = pkrn(f1.z * 0.125f, f1.w * 0.125f);
        qf[s] = tmp.v;
      }
    }

    unsigned short* pbase = Plds + w * 16 * PSTR;
    int srow = tid >> 2, scol = (tid & 3) * 16;
    const float* gk = kin + ((size_t)(b * NN + jbase + srow)) * DD + scol;        // fp32 K
    const unsigned short* gv = vtbf + ((size_t)b * DD + srow) * NN + jbase + scol;

    float4 kn[4]; uint4 vn[2];
#pragma unroll
    for (int i = 0; i < 4; i++) kn[i] = ((const float4*)gk)[i];
#pragma unroll
    for (int i = 0; i < 2; i++) vn[i] = ((const uint4*)gv)[i];

    // convert first K tile (registers), copy V
    uint4 kc[2]; uint4 vc[2];
#pragma unroll
    for (int s = 0; s < 2; s++) {
      union { uint4 u4; uint32_t x[4]; } kw;
      kw.x[0] = pkrn(kn[2*s].x, kn[2*s].y);
      kw.x[1] = pkrn(kn[2*s].z, kn[2*s].w);
      kw.x[2] = pkrn(kn[2*s+1].x, kn[2*s+1].y);
      kw.x[3] = pkrn(kn[2*s+1].z, kn[2*s+1].w);
      kc[s] = kw.u4;
      vc[s] = vn[s];
    }

    for (int it = 0; it < niter; ++it) {
      int j0 = jbase + it * BN;
      __syncthreads();                 // prior tile consumed
      *(uint4*)&Klds[srow * KSTR + scol]     = kc[0];
      *(uint4*)&Klds[srow * KSTR + scol + 8] = kc[1];
      *(uint4*)&Vlds[srow * KSTR + scol]     = vc[0];
      *(uint4*)&Vlds[srow * KSTR + scol + 8] = vc[1];
      bool more = (it + 1 < niter);
      if (more) {                      // prefetch next tile (fp32 K, bf16 Vt)
        gk += BN * DD; gv += BN;
#pragma unroll
        for (int i = 0; i < 4; i++) kn[i] = ((const float4*)gk)[i];
#pragma unroll
        for (int i = 0; i < 2; i++) vn[i] = ((const uint4*)gv)[i];
      }
      __syncthreads();

      // S^T = K . Q^T
      f32x4 s[4] = {{0,0,0,0},{0,0,0,0},{0,0,0,0},{0,0,0,0}};
#pragma unroll
      for (int c = 0; c < 4; c++) {
#pragma unroll
        for (int ss = 0; ss < 2; ss++) {
          short8 kf = *(const short8*)&Klds[(c * 16 + m) * KSTR + ss * 32 + quad * 8];
          s[c] = __builtin_amdgcn_mfma_f32_16x16x32_bf16(kf, qf[ss], s[c], 0, 0, 0);
        }
      }

      // P: masked score -> weight CM
#pragma unroll
      for (int c = 0; c < 4; c++) {
        float e[4];
#pragma unroll
        for (int rr = 0; rr < 4; rr++) {
          int j = j0 + c * 16 + quad * 4 + rr;
          float arg = (j < vq) ? s[c][rr] : 1.0e-6f;
          e[rr] = __expf(arg);
        }
        z += (e[0] + e[1]) + (e[2] + e[3]);
        *(uint2*)&pbase[m * PSTR + c * 16 + quad * 4] =
            make_uint2(pkrn(e[0], e[1]), pkrn(e[2], e[3]));
      }

      __builtin_amdgcn_s_waitcnt(0xc07f);  // lgkmcnt(0): wave-local P RAW

      // O^T = V^T . P^T
#pragma unroll
      for (int ss = 0; ss < 2; ss++) {
        short8 pf = *(const short8*)&pbase[m * PSTR + ss * 32 + quad * 8];
#pragma unroll
        for (int t = 0; t < 4; t++) {
          short8 vf = *(const short8*)&Vlds[(t * 16 + m) * KSTR + ss * 32 + quad * 8];
          o[t] = __builtin_amdgcn_mfma_f32_16x16x32_bf16(vf, pf, o[t], 0, 0, 0);
        }
      }

      // convert prefetched K OFF the staging window (loads landed during compute)
      if (more) {
#pragma unroll
        for (int s2 = 0; s2 < 2; s2++) {
          union { uint4 u4; uint32_t x[4]; } kw;
          kw.x[0] = pkrn(kn[2*s2].x, kn[2*s2].y);
          kw.x[1] = pkrn(kn[2*s2].z, kn[2*s2].w);
          kw.x[2] = pkrn(kn[2*s2+1].x, kn[2*s2+1].y);
          kw.x[3] = pkrn(kn[2*s2+1].z, kn[2*s2+1].w);
          kc[s2] = kw.u4;
          vc[s2] = vn[s2];
        }
      }
    }
  }

  // z: sum over quads, then closed-form masked remainder of this range
  z += __shfl_xor(z, 16);
  z += __shfl_xor(z, 32);
  z += CM * (float)(rangeEnd - (Tp << 6));

  // O += CM * (suf[Tp] - suf[rangeEnd/64]) at this lane's d positions
  {
    const float* sh = suf + ((size_t)b * 33 + Tp) * 64;
    const float* se = suf + ((size_t)b * 33 + (rangeEnd >> 6)) * 64;
#pragma unroll
    for (int t = 0; t < 4; t++) {
      float4 a = *(const float4*)&sh[t * 16 + quad * 4];
      float4 e4 = *(const float4*)&se[t * 16 + quad * 4];
      o[t][0] += CM * (a.x - e4.x);
      o[t][1] += CM * (a.y - e4.y);
      o[t][2] += CM * (a.z - e4.z);
      o[t][3] += CM * (a.w - e4.w);
    }
  }

  if (NS > 1) {
    // partials in RANK space (coalesced)
    int rrow = i0 + w * 16 + m;
    unsigned short* op = po + ((size_t)((sp * BB + b) * NN) + rrow) * DD;
#pragma unroll
    for (int t = 0; t < 4; t++)
      *(uint2*)&op[t * 16 + quad * 4] = make_uint2(pkrn(o[t][0], o[t][1]),
                                                   pkrn(o[t][2], o[t][3]));
    if (quad == 0) pz[(size_t)(sp * BB + b) * NN + rrow] = z;

    // split-K fixup: last block of this (b,qt) group merges all NS partials
    __threadfence();                              // release partials (device scope)
    if (tid == 0)
      lastFlag = (atomicAdd(&cnt[b * 32 + qt], 1) == NS - 1);
    __syncthreads();
    if (lastFlag) {
      __threadfence();                            // acquire other blocks' partials
      int row = tid >> 2, db = (tid & 3) * 16;    // 4 threads/row x 16 d
      int rank = i0 + row;
      float zs = 0.0f;
#pragma unroll
      for (int s2 = 0; s2 < NS; s2++) zs += pz[(size_t)(s2 * BB + b) * NN + rank];
      float inv = 1.0f / zs;
      float acc[16] = {0,0,0,0,0,0,0,0,0,0,0,0,0,0,0,0};
#pragma unroll
      for (int s2 = 0; s2 < NS; s2++) {
        const unsigned short* pp = po + ((size_t)((s2 * BB + b) * NN) + rank) * DD + db;
        uint4 a0 = *(const uint4*)pp;
        uint4 a1 = *(const uint4*)(pp + 8);
        uint32_t w8[8] = {a0.x, a0.y, a0.z, a0.w, a1.x, a1.y, a1.z, a1.w};
#pragma unroll
        for (int i = 0; i < 8; i++) {
          acc[2*i]   += __uint_as_float(w8[i] << 16);
          acc[2*i+1] += __uint_as_float(w8[i] & 0xffff0000u);
        }
      }
      int qrow = perm[b * NN + rank];
      float* outp = out + ((size_t)b * NN + qrow) * DD + db;
#pragma unroll
      for (int c = 0; c < 4; c++)
        *(float4*)&outp[c * 4] = make_float4(acc[c*4]*inv, acc[c*4+1]*inv,
                                             acc[c*4+2]*inv, acc[c*4+3]*inv);
    }
  } else {
    float inv = 1.0f / z;
    int qrow = pidx[w * 16 + m];
    float* op2 = out + ((size_t)b * NN + qrow) * DD;
#pragma unroll
    for (int t = 0; t < 4; t++)
      *(float4*)&op2[t * 16 + quad * 4] =
          make_float4(o[t][0]*inv, o[t][1]*inv, o[t][2]*inv, o[t][3]*inv);
  }
}

extern "C" void kernel_launch(void* const* d_in, const int* in_sizes, int n_in,
                              void* d_out, int out_size, void* d_ws, size_t ws_size,
                              hipStream_t stream) {
  const float* q = (const float*)d_in[0];
  const float* k = (const float*)d_in[1];
  const float* v = (const float*)d_in[2];
  const int* valid = (const int*)d_in[3];
  float* out = (float*)d_out;

  unsigned short* vtbf = (unsigned short*)d_ws;                    // 4 MB
  unsigned short* po   = vtbf + (size_t)BB * NN * DD;              // 4 x 4 MB bf16 partials
  float* pz   = (float*)(po + (size_t)4 * BB * NN * DD);           // 512 KB
  int*   perm = (int*)(pz + (size_t)4 * BB * NN);                  // 128 KB
  int*   sv   = perm + (size_t)BB * NN;                            // 128 KB
  float* suf  = (float*)(sv + (size_t)BB * NN);                    // 135 KB
  int*   cnt  = (int*)(suf + (size_t)BB * 33 * DD);                // 2 KB

  size_t need = ((char*)(cnt + BB * 32)) - (char*)d_ws;

  hipLaunchKernelGGL(prep_kernel, dim3(592), dim3(256), 0, stream,
                     v, valid, vtbf, perm, sv, suf, cnt);
  if (ws_size >= need) {
    hipLaunchKernelGGL((attn_kernel<4>), dim3(16 * 32 * 4), dim3(256), 0, stream,
                       q, k, vtbf, perm, sv, suf, out, po, pz, cnt);
  } else {
    hipLaunchKernelGGL((attn_kernel<1>), dim3(16 * 32), dim3(256), 0, stream,
                       q, k, vtbf, perm, sv, suf, out, po, pz, cnt);
  }
}

// Round 11
// 115.408 us; speedup vs baseline: 4.3327x; 4.3327x over previous
//
#include <hip/hip_runtime.h>
#include <hip/hip_bf16.h>
#include <stdint.h>

#define BB 16
#define NN 2048
#define DD 64
#define BM 64
#define BN 64
#define KSTR 72   // K/Vt LDS row stride in bf16 elems (144 B: 16B-aligned)
#define PSTR 72   // P LDS row stride

typedef __attribute__((ext_vector_type(8))) short short8;
typedef __attribute__((ext_vector_type(4))) float f32x4;

__device__ __forceinline__ unsigned short f2bf(float f) {   // RNE
  union { float f; uint32_t u; } c; c.f = f;
  uint32_t u = c.u + 0x7fffu + ((c.u >> 16) & 1u);
  return (unsigned short)(u >> 16);
}
__device__ __forceinline__ uint32_t pkrn(float a, float b) { // packed f32x2 -> bf16x2
  union { __hip_bfloat162 h; uint32_t u; } c;
  c.h = __float22bfloat162_rn(make_float2(a, b));
  return c.u;
}

#define QSCALE 0.18033688f   // 0.125 * log2(e): scores emerge in log2 units
#define CMW 1.0000010f       // exp(1e-6): masked-key weight (NOT zero)

// ---- fused pre-pass ----
// blocks [0,512):      K fp32->bf16 copy (4 float4/thread)
// blocks [512,1024):   V fp32 -> bf16 transposed vt[b][d][key]
// blocks [1024,1040):  per-batch counting sort of queries by valid
// blocks [1040,1104):  V fp32 tile-suffix sums suf[b][t][d], t=0..32
__global__ __launch_bounds__(256) void prep_kernel(const float* __restrict__ k,
                                                   const float* __restrict__ v,
                                                   const int* __restrict__ valid,
                                                   unsigned short* __restrict__ kbf,
                                                   unsigned short* __restrict__ vt,
                                                   int* __restrict__ perm,
                                                   int* __restrict__ sval,
                                                   float* __restrict__ suf) {
  __shared__ float t[64][65];
  __shared__ int hist[2048];
  __shared__ int part[256];
  __shared__ float ts[32][16];
  int id = blockIdx.x, tid = threadIdx.x;
  if (id < 512) {
#pragma unroll
    for (int r = 0; r < 4; r++) {
      int i = (id * 4 + r) * 256 + tid;      // 524288 float4s total
      float4 f = ((const float4*)k)[i];
      ushort4 o;
      o.x = f2bf(f.x); o.y = f2bf(f.y); o.z = f2bf(f.z); o.w = f2bf(f.w);
      ((ushort4*)kbf)[i] = o;
    }
  } else if (id < 1024) {
    int bid = id - 512;
    int b = bid >> 5;
    int k0 = (bid & 31) * 64;
    const float4* src = (const float4*)(v + ((size_t)b * NN + k0) * DD);
#pragma unroll
    for (int i = 0; i < 4; i++) {
      int f4 = tid + i * 256;
      int row = f4 >> 4, c4 = f4 & 15;
      float4 f = src[f4];
      t[row][c4*4+0] = f.x; t[row][c4*4+1] = f.y; t[row][c4*4+2] = f.z; t[row][c4*4+3] = f.w;
    }
    __syncthreads();
    int d = tid >> 2, kg = tid & 3;
    unsigned short* dst = vt + ((size_t)b * DD + d) * NN + k0 + kg * 16;
#pragma unroll
    for (int u = 0; u < 4; u++) {
      ushort4 o;
      o.x = f2bf(t[kg*16+u*4+0][d]);
      o.y = f2bf(t[kg*16+u*4+1][d]);
      o.z = f2bf(t[kg*16+u*4+2][d]);
      o.w = f2bf(t[kg*16+u*4+3][d]);
      ((ushort4*)dst)[u] = o;
    }
  } else if (id < 1040) {
    // counting sort of queries by valid, ascending
    int b = id - 1024;
    for (int i = tid; i < 2048; i += 256) hist[i] = 0;
    __syncthreads();
    for (int i = tid; i < NN; i += 256) atomicAdd(&hist[valid[b * NN + i]], 1);
    __syncthreads();
    int base = tid * 8, loc[8], s = 0;
#pragma unroll
    for (int j = 0; j < 8; j++) { loc[j] = s; s += hist[base + j]; }
    part[tid] = s;
    __syncthreads();
    if (tid == 0) {
      int run = 0;
      for (int t2 = 0; t2 < 256; t2++) { int tmp = part[t2]; part[t2] = run; run += tmp; }
    }
    __syncthreads();
#pragma unroll
    for (int j = 0; j < 8; j++) hist[base + j] = part[tid] + loc[j];
    __syncthreads();
    for (int i = tid; i < NN; i += 256) {
      int vv = valid[b * NN + i];
      int pos = atomicAdd(&hist[vv], 1);
      perm[b * NN + pos] = i;
      sval[b * NN + pos] = vv;
    }
  } else {
    // fp32 V suffix sums at 64-key tile granularity: suf[b][t][d] = sum_{j>=t*64} V[b][j][d]
    int sb = id - 1040;              // 64 blocks: b = sb>>2, d-group = sb&3
    int b = sb >> 2, dg = sb & 3;
    for (int p = tid; p < 512; p += 256) {
      int tt = p >> 4, d0 = p & 15;
      const float* vp = v + ((size_t)b * NN + tt * 64) * DD + dg * 16 + d0;
      float s = 0.0f;
#pragma unroll 8
      for (int r = 0; r < 64; r++) s += vp[(size_t)r * DD];
      ts[tt][d0] = s;
    }
    __syncthreads();
    if (tid < 16) {
      int d = dg * 16 + tid;
      float acc = 0.0f;
      suf[((size_t)b * 33 + 32) * 64 + d] = 0.0f;
      for (int tt = 31; tt >= 0; tt--) {
        acc += ts[tt][tid];
        suf[((size_t)b * 33 + tt) * 64 + d] = acc;
      }
    }
  }
}

// ---- main flash-attention, rank-sorted queries + suffix shortcut, split-K.
// ---- R7 semantics: EVERY split block writes its po/pz partials (blocks whose
// ---- range is fully masked write closed-form-only partials). No early exit —
// ---- output must not depend on prior workspace state (R10 tripwire lesson).
template <int NS>
__global__ __launch_bounds__(256, 4) void attn_kernel(
    const float* __restrict__ q, const unsigned short* __restrict__ kbf,
    const unsigned short* __restrict__ vtbf, const int* __restrict__ perm,
    const int* __restrict__ sval, const float* __restrict__ suf,
    float* __restrict__ out, unsigned short* __restrict__ po,
    float* __restrict__ pz)
{
  constexpr int JLEN = NN / NS;

  __shared__ __align__(16) unsigned short Klds[BN * KSTR];
  __shared__ __align__(16) unsigned short Vlds[DD * KSTR];
  __shared__ __align__(16) unsigned short Plds[4 * 16 * PSTR];
  __shared__ int vld[BM];
  __shared__ int pidx[BM];

  // decode: id&7 = XCD; heavy rank-tiles (large valid) dispatch first
  int id = blockIdx.x;
  int b = (id & 7) + 8 * ((id >> 3) & 1);
  int rest = id >> 4;                 // [0, 32*NS)
  int sp = rest % NS;
  int qt = 31 - (rest / NS);          // reversed: heavy blocks first
  int i0 = qt * BM;                   // RANK base (sorted by valid)
  int jbase = sp * JLEN;
  int rangeEnd = jbase + JLEN;

  int tid = threadIdx.x;
  int w = tid >> 6, lane = tid & 63;
  int m = lane & 15, quad = lane >> 4;

  if (tid < BM) {
    vld[tid]  = sval[b * NN + i0 + tid];
    pidx[tid] = perm[b * NN + i0 + tid];
  }
  int maxv = sval[b * NN + i0 + 63];  // sorted ascending -> block max (uniform)
  int jcov = ((maxv + 63) >> 6) << 6; // keys needing per-key scores
  int niter = (min(rangeEnd, jcov) - jbase) >> 6;
  if (niter < 0) niter = 0;
  int Tp = (jbase >> 6) + niter;      // first closed-form tile in this range

  __syncthreads();

  f32x4 o[4] = {{0,0,0,0},{0,0,0,0},{0,0,0,0},{0,0,0,0}};
  float z = 0.0f;

  if (niter > 0) {
    int vq = vld[w * 16 + m];
    int qrow = pidx[w * 16 + m];

    // Q fragment (B-operand layout), scale 0.125*log2e folded, fp32->bf16
    short8 qf[2];
    {
      const float* qp = q + ((size_t)b * NN + qrow) * DD;
#pragma unroll
      for (int s = 0; s < 2; s++) {
        float4 f0 = *(const float4*)(qp + s * 32 + quad * 8);
        float4 f1 = *(const float4*)(qp + s * 32 + quad * 8 + 4);
        union { short8 v; uint32_t x[4]; } tmp;
        tmp.x[0] = pkrn(f0.x * QSCALE, f0.y * QSCALE);
        tmp.x[1] = pkrn(f0.z * QSCALE, f0.w * QSCALE);
        tmp.x[2] = pkrn(f1.x * QSCALE, f1.y * QSCALE);
        tmp.x[3] = pkrn(f1.z * QSCALE, f1.w * QSCALE);
        qf[s] = tmp.v;
      }
    }

    unsigned short* pbase = Plds + w * 16 * PSTR;
    int srow = tid >> 2, scol = (tid & 3) * 16;
    const unsigned short* gk = kbf + ((size_t)(b * NN + jbase + srow)) * DD + scol;
    const unsigned short* gv = vtbf + ((size_t)b * DD + srow) * NN + jbase + scol;

    uint4 ka = *(const uint4*)gk, kb2 = *(const uint4*)(gk + 8);
    uint4 va = *(const uint4*)gv, vb2 = *(const uint4*)(gv + 8);

    for (int it = 0; it < niter; ++it) {
      int j0 = jbase + it * BN;
      __syncthreads();
      *(uint4*)&Klds[srow * KSTR + scol]     = ka;
      *(uint4*)&Klds[srow * KSTR + scol + 8] = kb2;
      *(uint4*)&Vlds[srow * KSTR + scol]     = va;
      *(uint4*)&Vlds[srow * KSTR + scol + 8] = vb2;
      if (it + 1 < niter) {
        gk += BN * DD; gv += BN;
        ka = *(const uint4*)gk; kb2 = *(const uint4*)(gk + 8);
        va = *(const uint4*)gv; vb2 = *(const uint4*)(gv + 8);
      }
      __syncthreads();

      // S^T = K . Q^T (scores in log2 units)
      f32x4 s[4] = {{0,0,0,0},{0,0,0,0},{0,0,0,0},{0,0,0,0}};
#pragma unroll
      for (int c = 0; c < 4; c++) {
#pragma unroll
        for (int ss = 0; ss < 2; ss++) {
          short8 kf = *(const short8*)&Klds[(c * 16 + m) * KSTR + ss * 32 + quad * 8];
          s[c] = __builtin_amdgcn_mfma_f32_16x16x32_bf16(kf, qf[ss], s[c], 0, 0, 0);
        }
      }

      // P: e^score = 2^(log2e*score); masked -> weight CMW
#pragma unroll
      for (int c = 0; c < 4; c++) {
        float e[4];
#pragma unroll
        for (int rr = 0; rr < 4; rr++) {
          int j = j0 + c * 16 + quad * 4 + rr;
          float ex = __builtin_amdgcn_exp2f(s[c][rr]);
          e[rr] = (j < vq) ? ex : CMW;
        }
        z += (e[0] + e[1]) + (e[2] + e[3]);
        *(uint2*)&pbase[m * PSTR + c * 16 + quad * 4] =
            make_uint2(pkrn(e[0], e[1]), pkrn(e[2], e[3]));
      }

      __builtin_amdgcn_s_waitcnt(0xc07f);  // lgkmcnt(0): wave-local P RAW

      // O^T = V^T . P^T
#pragma unroll
      for (int ss = 0; ss < 2; ss++) {
        short8 pf = *(const short8*)&pbase[m * PSTR + ss * 32 + quad * 8];
#pragma unroll
        for (int t = 0; t < 4; t++) {
          short8 vf = *(const short8*)&Vlds[(t * 16 + m) * KSTR + ss * 32 + quad * 8];
          o[t] = __builtin_amdgcn_mfma_f32_16x16x32_bf16(vf, pf, o[t], 0, 0, 0);
        }
      }
    }
  }

  // z: sum over quads, then closed-form masked remainder of this range
  z += __shfl_xor(z, 16);
  z += __shfl_xor(z, 32);
  z += CMW * (float)(rangeEnd - (Tp << 6));

  // O += CMW * (suf[Tp] - suf[rangeEnd/64]) at this lane's d positions
  {
    const float* sh = suf + ((size_t)b * 33 + Tp) * 64;
    const float* se = suf + ((size_t)b * 33 + (rangeEnd >> 6)) * 64;
#pragma unroll
    for (int t = 0; t < 4; t++) {
      float4 a = *(const float4*)&sh[t * 16 + quad * 4];
      float4 e4 = *(const float4*)&se[t * 16 + quad * 4];
      o[t][0] += CMW * (a.x - e4.x);
      o[t][1] += CMW * (a.y - e4.y);
      o[t][2] += CMW * (a.z - e4.z);
      o[t][3] += CMW * (a.w - e4.w);
    }
  }

  if (NS > 1) {
    // partials in RANK space -> coalesced; combine scatters via perm
    int rrow = i0 + w * 16 + m;
    unsigned short* op = po + ((size_t)((sp * BB + b) * NN) + rrow) * DD;
#pragma unroll
    for (int t = 0; t < 4; t++)
      *(uint2*)&op[t * 16 + quad * 4] = make_uint2(pkrn(o[t][0], o[t][1]),
                                                   pkrn(o[t][2], o[t][3]));
    if (quad == 0) pz[(size_t)(sp * BB + b) * NN + rrow] = z;
  } else {
    float inv = 1.0f / z;
    int qrow = pidx[w * 16 + m];
    float* op2 = out + ((size_t)b * NN + qrow) * DD;
#pragma unroll
    for (int t = 0; t < 4; t++)
      *(float4*)&op2[t * 16 + quad * 4] =
          make_float4(o[t][0]*inv, o[t][1]*inv, o[t][2]*inv, o[t][3]*inv);
  }
}

// ---- combine (R7-verified): out[perm[rank]] = sum_sp po / sum_sp pz ----
template <int NS>
__global__ __launch_bounds__(256) void combine_kernel(const unsigned short* __restrict__ po,
                                                      const float* __restrict__ pz,
                                                      const int* __restrict__ perm,
                                                      float* __restrict__ out) {
  int gid = blockIdx.x * 256 + threadIdx.x;   // 262144 threads x 8 elems
  size_t base = (size_t)gid * 8;
  int rowr = gid >> 3;                        // b*NN + rank
  float r[8] = {0,0,0,0,0,0,0,0};
  float zs = 0.0f;
#pragma unroll
  for (int sp = 0; sp < NS; sp++) {
    uint4 a = *(const uint4*)(po + (size_t)sp * BB * NN * DD + base);
    zs += pz[(size_t)sp * BB * NN + rowr];
    uint32_t aw[4] = {a.x, a.y, a.z, a.w};
#pragma unroll
    for (int i = 0; i < 4; i++) {
      r[2*i]   += __uint_as_float(aw[i] << 16);
      r[2*i+1] += __uint_as_float(aw[i] & 0xffff0000u);
    }
  }
  float inv = 1.0f / zs;
  int b = rowr >> 11;                         // NN = 2048
  int qrow = perm[rowr];
  float* op = out + ((size_t)(b * NN + qrow)) * DD + (gid & 7) * 8;
  *(float4*)&op[0] = make_float4(r[0]*inv, r[1]*inv, r[2]*inv, r[3]*inv);
  *(float4*)&op[4] = make_float4(r[4]*inv, r[5]*inv, r[6]*inv, r[7]*inv);
}

extern "C" void kernel_launch(void* const* d_in, const int* in_sizes, int n_in,
                              void* d_out, int out_size, void* d_ws, size_t ws_size,
                              hipStream_t stream) {
  const float* q = (const float*)d_in[0];
  const float* k = (const float*)d_in[1];
  const float* v = (const float*)d_in[2];
  const int* valid = (const int*)d_in[3];
  float* out = (float*)d_out;

  unsigned short* kbf  = (unsigned short*)d_ws;                    // 4 MB
  unsigned short* vtbf = kbf + (size_t)BB * NN * DD;               // 4 MB
  unsigned short* po   = vtbf + (size_t)BB * NN * DD;              // 4 x 4 MB bf16 partials
  float* pz   = (float*)(po + (size_t)4 * BB * NN * DD);           // 512 KB
  int*   perm = (int*)(pz + (size_t)4 * BB * NN);                  // 128 KB
  int*   sv   = perm + (size_t)BB * NN;                            // 128 KB
  float* suf  = (float*)(sv + (size_t)BB * NN);                    // 135 KB

  size_t need4 = ((char*)(suf + (size_t)BB * 33 * DD)) - (char*)d_ws;

  hipLaunchKernelGGL(prep_kernel, dim3(1104), dim3(256), 0, stream,
                     k, v, valid, kbf, vtbf, perm, sv, suf);
  if (ws_size >= need4) {
    hipLaunchKernelGGL((attn_kernel<4>), dim3(16 * 32 * 4), dim3(256), 0, stream,
                       q, kbf, vtbf, perm, sv, suf, out, po, pz);
    hipLaunchKernelGGL((combine_kernel<4>), dim3(1024), dim3(256), 0, stream,
                       po, pz, perm, out);
  } else {
    hipLaunchKernelGGL((attn_kernel<1>), dim3(16 * 32), dim3(256), 0, stream,
                       q, kbf, vtbf, perm, sv, suf, out, po, pz);
  }
}